// Round 1
// 146.389 us; speedup vs baseline: 1.0527x; 1.0527x over previous
//
#include <hip/hip_runtime.h>

#define H_IMG 1080
#define W_IMG 1920
#define HW_PIX (H_IMG * W_IMG)
#define GY 16
#define GX 16
#define GL 8
#define CF 12          // floats per grid cell
#define SEG 192        // pixels per block (3 waves); 1920 = 10*192 exactly

// Block = one image row x 192 pixels. y-interp is uniform per row; the 192-px
// span covers at most 4 grid x-cells. Stage G'[xi][z][c] = lerp_y(grid) in LDS
// (4*8*3 float4 = 1.5KB), each pixel does 4 LDS cells instead of 8 global.
//
// R1 change: outputs (12 affine + 3 res floats / px) round-trip through LDS so
// global stores are DENSE 16B/lane dwordx4 (previously 48B/12B lane-strided
// partial-line stores -> store-transaction-bound at ~1.9 TB/s). Input rgb is
// staged via float4 loads (16B/lane) into LDS too.
__global__ __launch_bounds__(192) void bg_kernel(
    const float* __restrict__ rgb,    // (3, H, W)
    const float* __restrict__ grids,  // (NUM, 16, 16, 8, 12)
    const int* __restrict__ idxp,
    float* __restrict__ out)          // [affine HW*12 | res HW*3]
{
    __shared__ float4 sg[96];            // [xi(4)][z(8)][c4(3)]  1.5 KB
    __shared__ float  s_in[3 * SEG];     // staged rgb            2.25 KB
    __shared__ float  s_aff[SEG * 12];   // affine out, pix-major 9 KB
    __shared__ float  s_res[SEG * 3];    // res out, pix-major    2.25 KB

    const int tid = threadIdx.x;
    const int y = blockIdx.y;
    const int xbase = blockIdx.x * SEG;
    const int p0 = y * W_IMG + xbase;    // multiple of 192 -> float4-aligned

    // ---- stage input: 3 channels x 48 float4 = 144 dense 16B/lane loads ----
    if (tid < 144) {
        const int ch = tid / 48;
        const int i  = tid - ch * 48;
        ((float4*)s_in)[ch * 48 + i] =
            ((const float4*)(rgb + (size_t)ch * HW_PIX + p0))[i];
    }

    const float* grid = grids + (size_t)idxp[0] * (GY * GX * GL * CF);

    // row-uniform y interpolation
    float gyv = (float)y * (15.0f / 1079.0f);
    float fy = floorf(gyv);
    float wy = gyv - fy;
    int y0 = min(max((int)fy, 0), GY - 1);
    int y1 = min(y0 + 1, GY - 1);

    // block-uniform first x-cell
    int xc0 = (int)floorf((float)xbase * (15.0f / 1919.0f));

    if (tid < 96) {
        int xi  = tid / 24;
        int rem = tid - xi * 24;
        int z   = rem / 3;
        int c4  = rem - z * 3;
        int xc  = min(xc0 + xi, GX - 1);
        const float4* c0 = (const float4*)(grid + (size_t)((y0 * GX + xc) * GL + z) * CF) + c4;
        const float4* c1 = (const float4*)(grid + (size_t)((y1 * GX + xc) * GL + z) * CF) + c4;
        float4 a = *c0, b = *c1;
        float wy0 = 1.0f - wy;
        float4 rr;
        rr.x = wy0 * a.x + wy * b.x;
        rr.y = wy0 * a.y + wy * b.y;
        rr.z = wy0 * a.z + wy * b.z;
        rr.w = wy0 * a.w + wy * b.w;
        sg[tid] = rr;
    }
    __syncthreads();

    const int x = xbase + tid;          // always < 1920 (10*192 grid)

    float r = s_in[tid];
    float g = s_in[SEG + tid];
    float b = s_in[2 * SEG + tid];

    float gray = 0.299f * r + 0.587f * g + 0.114f * b;

    float gxv = (float)x * (15.0f / 1919.0f);
    float fx = floorf(gxv), wx = gxv - fx;
    float gz = fminf(fmaxf(gray, 0.0f), 1.0f) * 7.0f;
    float fz = floorf(gz), wz = gz - fz;

    int x0g = min(max((int)fx, 0), GX - 1);
    int x1g = min(x0g + 1, GX - 1);
    int xi0 = x0g - xc0;                // in [0,3]
    int xi1 = x1g - xc0;                // in [0,3]
    int z0 = min(max((int)fz, 0), GL - 1);
    int z1 = min(z0 + 1, GL - 1);

    float w00 = (1.0f - wx) * (1.0f - wz);
    float w01 = (1.0f - wx) * wz;
    float w10 = wx * (1.0f - wz);
    float w11 = wx * wz;

    const float4* A = sg + (xi0 * 24 + z0 * 3);
    const float4* B = sg + (xi0 * 24 + z1 * 3);
    const float4* C = sg + (xi1 * 24 + z0 * 3);
    const float4* D = sg + (xi1 * 24 + z1 * 3);

    float4 acc[3];
#pragma unroll
    for (int j = 0; j < 3; ++j) {
        float4 va = A[j], vb = B[j], vc = C[j], vd = D[j];
        float4 o;
        o.x = fmaf(w00, va.x, fmaf(w01, vb.x, fmaf(w10, vc.x, w11 * vd.x)));
        o.y = fmaf(w00, va.y, fmaf(w01, vb.y, fmaf(w10, vc.y, w11 * vd.y)));
        o.z = fmaf(w00, va.z, fmaf(w01, vb.z, fmaf(w10, vc.z, w11 * vd.z)));
        o.w = fmaf(w00, va.w, fmaf(w01, vb.w, fmaf(w10, vc.w, w11 * vd.w)));
        acc[j] = o;
    }

    // ---- outputs to LDS (pix-major = global layout order) ----
    // affine writes: 12-dword lane stride -> 8 lanes per 4-bank group, uniform
    float4* sa = (float4*)(s_aff + tid * 12);   // 48B-aligned
    sa[0] = acc[0];
    sa[1] = acc[1];
    sa[2] = acc[2];

    // res_rgb = A[:, :3] @ rgb + A[:, 3]
    s_res[tid * 3 + 0] = fmaf(acc[0].x, r, fmaf(acc[0].y, g, fmaf(acc[0].z, b, acc[0].w)));
    s_res[tid * 3 + 1] = fmaf(acc[1].x, r, fmaf(acc[1].y, g, fmaf(acc[1].z, b, acc[1].w)));
    s_res[tid * 3 + 2] = fmaf(acc[2].x, r, fmaf(acc[2].y, g, fmaf(acc[2].z, b, acc[2].w)));

    __syncthreads();

    // ---- dense drain: 16B/lane, fully coalesced ----
    const float4* sa4 = (const float4*)s_aff;        // 576 float4
    float4* ao = (float4*)(out + (size_t)p0 * 12);   // block region: 9216 B contiguous
    ao[tid]           = sa4[tid];
    ao[tid + SEG]     = sa4[tid + SEG];
    ao[tid + 2 * SEG] = sa4[tid + 2 * SEG];

    if (tid < 144) {                                  // 2304 B contiguous
        ((float4*)(out + (size_t)HW_PIX * 12 + (size_t)p0 * 3))[tid] =
            ((const float4*)s_res)[tid];
    }
}

extern "C" void kernel_launch(void* const* d_in, const int* in_sizes, int n_in,
                              void* d_out, int out_size, void* d_ws, size_t ws_size,
                              hipStream_t stream) {
    const float* rgb   = (const float*)d_in[0];
    const float* grids = (const float*)d_in[1];
    const int*   idx   = (const int*)d_in[2];
    float*       out   = (float*)d_out;

    dim3 grid(W_IMG / SEG, H_IMG);   // (10, 1080)
    dim3 block(SEG);
    bg_kernel<<<grid, block, 0, stream>>>(rgb, grids, idx, out);
}

// Round 2
// 144.869 us; speedup vs baseline: 1.0638x; 1.0105x over previous
//
#include <hip/hip_runtime.h>

#define H_IMG 1080
#define W_IMG 1920
#define HW_PIX (H_IMG * W_IMG)
#define GY 16
#define GX 16
#define GL 8
#define CF 12          // floats per grid cell
#define SEG 320        // pixels per block (5 waves); 1920 = 6*320 exactly

// Block = one image row x 320 pixels. y-interp is uniform per row; the 320-px
// span covers exactly grid x-cells xc0..xc0+3 (320*15/1919 = 2.49, and the six
// xbase values' fractional parts keep floor(gx) <= xc0+2, x1 <= xc0+3).
// Stage G'[xi][z][c] = lerp_y(grid) in LDS (4*8*3 float4 = 1.5KB); each pixel
// does 4 LDS cells instead of 8 global.
//
// R2: SEG 192->320 (fewer blocks/barriers per px, staging amortized 1.67x),
// input rgb loaded directly per-pixel (dense 4B/lane) and issued BEFORE the
// grid staging so HBM latency hides under it — the kernel is per-wave-stall
// bound, not BW bound (fills hit 85% peak at 10% occupancy; we were at 2 TB/s
// with 30 waves/CU). Output LDS transpose + dense dwordx4 drain kept from R1.
__global__ __launch_bounds__(320) void bg_kernel(
    const float* __restrict__ rgb,    // (3, H, W)
    const float* __restrict__ grids,  // (NUM, 16, 16, 8, 12)
    const int* __restrict__ idxp,
    float* __restrict__ out)          // [affine HW*12 | res HW*3]
{
    __shared__ float4 sg[96];            // [xi(4)][z(8)][c4(3)]  1.5 KB
    __shared__ float  s_aff[SEG * 12];   // affine out, pix-major 15 KB
    __shared__ float  s_res[SEG * 3];    // res out, pix-major    3.75 KB

    const int tid = threadIdx.x;
    const int y = blockIdx.y;
    const int xbase = blockIdx.x * SEG;
    const int p0 = y * W_IMG + xbase;    // multiple of 320 -> float4-aligned
    const int x = xbase + tid;
    const int p = p0 + tid;

    // ---- issue pixel loads FIRST: latency hides under grid staging ----
    float r = rgb[p];
    float g = rgb[HW_PIX + p];
    float b = rgb[2 * HW_PIX + p];

    const float* grid = grids + (size_t)idxp[0] * (GY * GX * GL * CF);

    // row-uniform y interpolation
    float gyv = (float)y * (15.0f / 1079.0f);
    float fy = floorf(gyv);
    float wy = gyv - fy;
    int y0 = min(max((int)fy, 0), GY - 1);
    int y1 = min(y0 + 1, GY - 1);

    // block-uniform first x-cell
    int xc0 = (int)floorf((float)xbase * (15.0f / 1919.0f));

    if (tid < 96) {
        int xi  = tid / 24;
        int rem = tid - xi * 24;
        int z   = rem / 3;
        int c4  = rem - z * 3;
        int xc  = min(xc0 + xi, GX - 1);
        const float4* c0 = (const float4*)(grid + (size_t)((y0 * GX + xc) * GL + z) * CF) + c4;
        const float4* c1 = (const float4*)(grid + (size_t)((y1 * GX + xc) * GL + z) * CF) + c4;
        float4 a = *c0, bb = *c1;
        float wy0 = 1.0f - wy;
        float4 rr;
        rr.x = wy0 * a.x + wy * bb.x;
        rr.y = wy0 * a.y + wy * bb.y;
        rr.z = wy0 * a.z + wy * bb.z;
        rr.w = wy0 * a.w + wy * bb.w;
        sg[tid] = rr;
    }
    __syncthreads();

    float gray = 0.299f * r + 0.587f * g + 0.114f * b;

    float gxv = (float)x * (15.0f / 1919.0f);
    float fx = floorf(gxv), wx = gxv - fx;
    float gz = fminf(fmaxf(gray, 0.0f), 1.0f) * 7.0f;
    float fz = floorf(gz), wz = gz - fz;

    int x0g = min(max((int)fx, 0), GX - 1);
    int x1g = min(x0g + 1, GX - 1);
    int xi0 = x0g - xc0;                // in [0,3]
    int xi1 = x1g - xc0;                // in [0,3]
    int z0 = min(max((int)fz, 0), GL - 1);
    int z1 = min(z0 + 1, GL - 1);

    float w00 = (1.0f - wx) * (1.0f - wz);
    float w01 = (1.0f - wx) * wz;
    float w10 = wx * (1.0f - wz);
    float w11 = wx * wz;

    const float4* A = sg + (xi0 * 24 + z0 * 3);
    const float4* B = sg + (xi0 * 24 + z1 * 3);
    const float4* C = sg + (xi1 * 24 + z0 * 3);
    const float4* D = sg + (xi1 * 24 + z1 * 3);

    float4 acc[3];
#pragma unroll
    for (int j = 0; j < 3; ++j) {
        float4 va = A[j], vb = B[j], vc = C[j], vd = D[j];
        float4 o;
        o.x = fmaf(w00, va.x, fmaf(w01, vb.x, fmaf(w10, vc.x, w11 * vd.x)));
        o.y = fmaf(w00, va.y, fmaf(w01, vb.y, fmaf(w10, vc.y, w11 * vd.y)));
        o.z = fmaf(w00, va.z, fmaf(w01, vb.z, fmaf(w10, vc.z, w11 * vd.z)));
        o.w = fmaf(w00, va.w, fmaf(w01, vb.w, fmaf(w10, vc.w, w11 * vd.w)));
        acc[j] = o;
    }

    // ---- outputs to LDS (pix-major = global layout order) ----
    // affine writes: 12-dword lane stride -> 8 lanes cover all 32 banks, uniform
    float4* sa = (float4*)(s_aff + tid * 12);   // 48B-aligned
    sa[0] = acc[0];
    sa[1] = acc[1];
    sa[2] = acc[2];

    // res_rgb = A[:, :3] @ rgb + A[:, 3]
    s_res[tid * 3 + 0] = fmaf(acc[0].x, r, fmaf(acc[0].y, g, fmaf(acc[0].z, b, acc[0].w)));
    s_res[tid * 3 + 1] = fmaf(acc[1].x, r, fmaf(acc[1].y, g, fmaf(acc[1].z, b, acc[1].w)));
    s_res[tid * 3 + 2] = fmaf(acc[2].x, r, fmaf(acc[2].y, g, fmaf(acc[2].z, b, acc[2].w)));

    __syncthreads();

    // ---- dense drain: 16B/lane, fully coalesced ----
    const float4* sa4 = (const float4*)s_aff;        // 960 float4
    float4* ao = (float4*)(out + (size_t)p0 * 12);   // block region: 15360 B contiguous
    ao[tid]           = sa4[tid];
    ao[tid + SEG]     = sa4[tid + SEG];
    ao[tid + 2 * SEG] = sa4[tid + 2 * SEG];

    if (tid < 240) {                                  // 3840 B contiguous
        ((float4*)(out + (size_t)HW_PIX * 12 + (size_t)p0 * 3))[tid] =
            ((const float4*)s_res)[tid];
    }
}

extern "C" void kernel_launch(void* const* d_in, const int* in_sizes, int n_in,
                              void* d_out, int out_size, void* d_ws, size_t ws_size,
                              hipStream_t stream) {
    const float* rgb   = (const float*)d_in[0];
    const float* grids = (const float*)d_in[1];
    const int*   idx   = (const int*)d_in[2];
    float*       out   = (float*)d_out;

    dim3 grid(W_IMG / SEG, H_IMG);   // (6, 1080)
    dim3 block(SEG);
    bg_kernel<<<grid, block, 0, stream>>>(rgb, grids, idx, out);
}